// Round 3
// baseline (247.439 us; speedup 1.0000x reference)
//
#include <hip/hip_runtime.h>
#include <cstdint>
#include <cstddef>

// Problem dims (fixed by the reference): B=64, S=512, D=768, C=512
#define BB 64
#define SS 512
#define DD 768
#define CC 512

typedef __attribute__((ext_vector_type(8))) short short8;
typedef __attribute__((ext_vector_type(4))) float f32x4;

#define GLOBAL_AS __attribute__((address_space(1)))
#define LDS_AS __attribute__((address_space(3)))

// float -> bf16 bits, round-to-nearest-even
static __device__ __forceinline__ unsigned short f2bf(float f) {
  union { float f; unsigned u; } v; v.f = f;
  unsigned u = v.u;
  u += 0x7FFFu + ((u >> 16) & 1u);
  return (unsigned short)(u >> 16);
}

// async 16B/lane global->LDS copy (wave-uniform LDS base + lane*16)
static __device__ __forceinline__ void async_copy16(const void* g, void* l) {
  __builtin_amdgcn_global_load_lds((const GLOBAL_AS void*)g, (LDS_AS void*)l,
                                   16, 0, 0);
}

// ---------------------------------------------------------------------------
// Kernel 1: normalize label embeddings -> bf16 rows, XOR-swizzled.
// Row c element d stored at ((d>>3) ^ (c&7))*8 + (d&7): 16B chunk j -> slot
// j^(c&7). Global row stays contiguous (for global_load_lds); the MFMA-layout
// ds_read_b128 becomes 8-phase optimal (no extra serialization).
// ---------------------------------------------------------------------------
__global__ __launch_bounds__(256) void k_label_norm(const float* __restrict__ L,
                                                    unsigned short* __restrict__ Lnb) {
  const int c = blockIdx.x;
  const int tid = threadIdx.x;
  const float* row = L + (size_t)c * DD;
  float v[3];
  float s = 0.f;
#pragma unroll
  for (int k = 0; k < 3; k++) { v[k] = row[tid + 256 * k]; s += v[k] * v[k]; }
#pragma unroll
  for (int o = 32; o > 0; o >>= 1) s += __shfl_xor(s, o, 64);
  __shared__ float wsum[4];
  if ((tid & 63) == 0) wsum[tid >> 6] = s;
  __syncthreads();
  const float tot = wsum[0] + wsum[1] + wsum[2] + wsum[3];
  const float inv = 1.f / fmaxf(sqrtf(tot), 1e-8f);
  unsigned short* orow = Lnb + (size_t)c * DD;
  const int sw = c & 7;
#pragma unroll
  for (int k = 0; k < 3; k++) {
    const int d = tid + 256 * k;
    const int idx = (((d >> 3) ^ sw) << 3) | (d & 7);
    orow[idx] = f2bf(v[k] * inv);
  }
}

// ---------------------------------------------------------------------------
// Kernel 2: m[b,s] = max_c dot(V[b,s,:], Ln[c,:]) / max(||V||,eps)
// 256 blocks x 8 waves x 16 tokens (128 tokens/block, 1 block/CU):
// halves L2 staging traffic vs 512 blocks (each block reads the full 768 KB
// Lnb once -> 200 MB total). A-fragments in registers (96 VGPR); double-
// buffered async global_load_lds staging of 16-class chunks (24 KB, 3 x 1KB
// instructions per wave). Inner loop has ZERO address VALU: the XOR swizzle
// factors into two lane-constant LDS pointers + compile-time immediates:
//   off(kc) = mr*768 + (q^(mr&3))*8 + ((kc^((mr>>2)&1))*32  [elems]
//           = elemBase + (u^swHi)*32 + t*64,  kc = 2t+u.
// ---------------------------------------------------------------------------
__global__ __launch_bounds__(512) void k_sims_max(const float* __restrict__ V,
                                                  const unsigned short* __restrict__ Lnb,
                                                  float* __restrict__ m_out) {
  const int tid = threadIdx.x;
  const int wave = tid >> 6;
  const int lane = tid & 63;
  const int q = lane >> 4;    // quad 0..3
  const int mr = lane & 15;   // row (token) for A, col (class) for B
  const int64_t tokBase = (int64_t)blockIdx.x * 128 + wave * 16;

  __shared__ unsigned short Bs[2][16 * DD];  // 2 x 24576 B
  __shared__ float nrmS[8][16];

  // ---- prefetch class-chunk 0 into buf 0 (async, in flight during A load)
  {
    const char* src = (const char*)Lnb;
    char* dst = (char*)&Bs[0][0];
#pragma unroll
    for (int i = wave; i < 24; i += 8)
      async_copy16(src + i * 1024 + lane * 16, dst + i * 1024);
  }

  // ---- load A fragments + squared norm
  const float* arow = V + (tokBase + mr) * DD + q * 8;
  short8 afrag[24];
  float nrm2 = 0.f;
#pragma unroll
  for (int kc = 0; kc < 24; kc++) {
    const float4* p = (const float4*)(arow + kc * 32);
    const float4 x = p[0];
    const float4 y = p[1];
    short8 a;
    a[0] = (short)f2bf(x.x); a[1] = (short)f2bf(x.y);
    a[2] = (short)f2bf(x.z); a[3] = (short)f2bf(x.w);
    a[4] = (short)f2bf(y.x); a[5] = (short)f2bf(y.y);
    a[6] = (short)f2bf(y.z); a[7] = (short)f2bf(y.w);
    afrag[kc] = a;
    nrm2 += x.x * x.x + x.y * x.y + x.z * x.z + x.w * x.w;
    nrm2 += y.x * y.x + y.y * y.y + y.z * y.z + y.w * y.w;
  }
  // lanes {m, m+16, m+32, m+48} each hold 1/4 of token m's sum of squares
  nrm2 += __shfl_xor(nrm2, 16, 64);
  nrm2 += __shfl_xor(nrm2, 32, 64);
  if (q == 0) nrmS[wave][mr] = nrm2;

  __syncthreads();  // buf0 staged (vmcnt drain) + nrmS visible

  // lane-constant LDS read bases (zero VALU in the MFMA loop)
  const int swLo = mr & 3;
  const int swHi = (mr >> 2) & 1;
  const int elemBase = mr * DD + ((q ^ swLo) << 3);
  const int u0off = swHi ? 32 : 0;   // (0 ^ swHi) * 32
  const int u1off = swHi ? 0 : 32;   // (1 ^ swHi) * 32

  f32x4 vmax = {-3e38f, -3e38f, -3e38f, -3e38f};
  for (int cc = 0; cc < 32; cc++) {
    const int p = cc & 1;
    // prefetch next chunk into the other buffer (its readers finished at the
    // barrier ending iteration cc-1)
    if (cc + 1 < 32) {
      const char* src = (const char*)(Lnb + (size_t)(cc + 1) * 16 * DD);
      char* dst = (char*)&Bs[p ^ 1][0];
#pragma unroll
      for (int i = wave; i < 24; i += 8)
        async_copy16(src + i * 1024 + lane * 16, dst + i * 1024);
    }
    const unsigned short* b0 = &Bs[p][elemBase + u0off];
    const unsigned short* b1 = &Bs[p][elemBase + u1off];
    f32x4 acc = {0.f, 0.f, 0.f, 0.f};
#pragma unroll
    for (int t = 0; t < 12; t++) {
      const short8 bu0 = *(const short8*)(b0 + t * 64);
      acc = __builtin_amdgcn_mfma_f32_16x16x32_bf16(afrag[2 * t], bu0, acc, 0, 0, 0);
      const short8 bu1 = *(const short8*)(b1 + t * 64);
      acc = __builtin_amdgcn_mfma_f32_16x16x32_bf16(afrag[2 * t + 1], bu1, acc, 0, 0, 0);
    }
    vmax[0] = fmaxf(vmax[0], acc[0]);
    vmax[1] = fmaxf(vmax[1], acc[1]);
    vmax[2] = fmaxf(vmax[2], acc[2]);
    vmax[3] = fmaxf(vmax[3], acc[3]);
    __syncthreads();  // drains prefetch vmcnt + guards buffer reuse
  }
  // reduce max over the 16 column-lanes of each quad
#pragma unroll
  for (int o = 1; o < 16; o <<= 1) {
#pragma unroll
    for (int r = 0; r < 4; r++) vmax[r] = fmaxf(vmax[r], __shfl_xor(vmax[r], o, 64));
  }
  // rows held by this quad are tokens q*4 + r
  if (mr == 0) {
#pragma unroll
    for (int r = 0; r < 4; r++) {
      const float nr = nrmS[wave][q * 4 + r];
      m_out[tokBase + q * 4 + r] = vmax[r] / fmaxf(sqrtf(nr), 1e-8f);
    }
  }
}

// ---------------------------------------------------------------------------
// Kernel 3: softmax over S per batch. grid = B blocks x 256 threads.
// ---------------------------------------------------------------------------
__global__ __launch_bounds__(256) void k_softmax(const float* __restrict__ m,
                                                 float* __restrict__ beta) {
  const int b = blockIdx.x;
  const int tid = threadIdx.x;
  const float* mb = m + (size_t)b * SS;
  const float v0 = mb[tid];
  const float v1 = mb[tid + 256];
  float mx = fmaxf(v0, v1);
#pragma unroll
  for (int o = 32; o > 0; o >>= 1) mx = fmaxf(mx, __shfl_xor(mx, o, 64));
  __shared__ float wred[4];
  if ((tid & 63) == 0) wred[tid >> 6] = mx;
  __syncthreads();
  mx = fmaxf(fmaxf(wred[0], wred[1]), fmaxf(wred[2], wred[3]));
  const float e0 = __expf(v0 - mx);
  const float e1 = __expf(v1 - mx);
  float s = e0 + e1;
#pragma unroll
  for (int o = 32; o > 0; o >>= 1) s += __shfl_xor(s, o, 64);
  __syncthreads();  // wred reuse hazard
  if ((tid & 63) == 0) wred[tid >> 6] = s;
  __syncthreads();
  s = wred[0] + wred[1] + wred[2] + wred[3];
  const float inv = 1.f / s;
  float* bb = beta + (size_t)b * SS;
  bb[tid] = e0 * inv;
  bb[tid + 256] = e1 * inv;
}

// ---------------------------------------------------------------------------
// Kernel 4: partial z over (batch, s-chunk). grid = B*nsc x 192 threads.
// Thread owns one float4 of D; second (and last) full read of V, coalesced.
// ---------------------------------------------------------------------------
__global__ __launch_bounds__(192) void k_zpart(const float* __restrict__ V,
                                               const float* __restrict__ beta,
                                               float* __restrict__ zpart,
                                               int spc, int nsc) {
  const int blk = blockIdx.x;
  const int b = blk / nsc;
  const int sc = blk % nsc;
  const int tid = threadIdx.x;
  const float* vb = V + ((size_t)b * SS + (size_t)sc * spc) * DD + tid * 4;
  const float* bb = beta + (size_t)b * SS + (size_t)sc * spc;
  float4 acc = {0.f, 0.f, 0.f, 0.f};
#pragma unroll 4
  for (int s = 0; s < spc; s++) {
    const float w = bb[s];
    const float4 x = *(const float4*)(vb + (size_t)s * DD);
    acc.x += w * x.x; acc.y += w * x.y; acc.z += w * x.z; acc.w += w * x.w;
  }
  *(float4*)(zpart + (size_t)blk * DD + tid * 4) = acc;
}

// ---------------------------------------------------------------------------
// Kernel 5: reduce z-partials -> z (to out), then out = z @ fc_w^T + fc_b.
// grid = 2*B blocks (b, class-half) x 256 threads; fc_w L2/L3-resident.
// ---------------------------------------------------------------------------
__global__ __launch_bounds__(256) void k_final(const float* __restrict__ zpart,
                                               const float* __restrict__ fc_w,
                                               const float* __restrict__ fc_b,
                                               float* __restrict__ out,
                                               float* __restrict__ zout,
                                               int nsc) {
  const int b = blockIdx.x >> 1;
  const int half = blockIdx.x & 1;
  const int tid = threadIdx.x;
  __shared__ float zs[DD];
  for (int i = tid; i < DD; i += 256) {
    float s = 0.f;
    for (int sc = 0; sc < nsc; sc++) s += zpart[((size_t)b * nsc + sc) * DD + i];
    zs[i] = s;
    if (half == 0) zout[(size_t)b * DD + i] = s;
  }
  __syncthreads();
  const int c = half * 256 + tid;
  const float4* w = (const float4*)(fc_w + (size_t)c * DD);
  float acc = 0.f;
  for (int d4 = 0; d4 < DD / 4; d4++) {
    const float4 ww = w[d4];
    acc += ww.x * zs[d4 * 4] + ww.y * zs[d4 * 4 + 1] +
           ww.z * zs[d4 * 4 + 2] + ww.w * zs[d4 * 4 + 3];
  }
  out[(size_t)b * CC + c] = acc + fc_b[c];
}

// ---------------------------------------------------------------------------
extern "C" void kernel_launch(void* const* d_in, const int* in_sizes, int n_in,
                              void* d_out, int out_size, void* d_ws, size_t ws_size,
                              hipStream_t stream) {
  const float* V  = (const float*)d_in[0];  // [64,512,768]
  const float* L  = (const float*)d_in[1];  // [512,768]
  const float* fw = (const float*)d_in[2];  // [512,768]
  const float* fb = (const float*)d_in[3];  // [512]
  float* out = (float*)d_out;               // [64*512] out, then [64*768] z

  char* ws = (char*)d_ws;
  unsigned short* Lnb = (unsigned short*)ws;            // 786432 B (swizzled)
  float* m     = (float*)(ws + 786432);                 // 131072 B
  float* beta  = (float*)(ws + 917504);                 // 131072 B
  float* zpart = (float*)(ws + 1048576);                // nsc*64*768*4 B

  // 16 s-chunks (4 MB total ws) if the workspace allows, else 8 (2.5 MB)
  const int nsc = (ws_size >= (size_t)1048576 + 16 * BB * DD * 4) ? 16 : 8;
  const int spc = SS / nsc;

  k_label_norm<<<CC, 256, 0, stream>>>(L, Lnb);
  k_sims_max<<<256, 512, 0, stream>>>(V, Lnb, m);
  k_softmax<<<BB, 256, 0, stream>>>(m, beta);
  k_zpart<<<BB * nsc, 192, 0, stream>>>(V, beta, zpart, spc, nsc);
  k_final<<<2 * BB, 256, 0, stream>>>(zpart, fw, fb, out, out + BB * CC, nsc);
}